// Round 7
// baseline (218.061 us; speedup 1.0000x reference)
//
#include <hip/hip_runtime.h>
#include <hip/hip_bf16.h>

// ---------------------------------------------------------------------------
// Attention_58248346469030:  out = softmax((x@Wq)(x@Wk)^T * sc) @ (x@Wv) @ Wout + b
// B=4, S=2048, DIM=1024, INNER=1024 (full-dim attention, no head split).
//
// Pipeline (fp16/bf16 MFMA, fp32 accumulate):
//   prep:  x -> fp16;  W_qkv -> fp16 transposed [n][k] (q pre-scaled by 0.125);
//          W_out -> fp16 transposed.
//   1) qkv  = x @ W_qkv       (q/k fp16 row-major; v bf16 written transposed->VT)
//   2) P    = exp(q @ k^T)    (fp16 MFMA, bf16 out; rowsum fused shfl+atomicAdd)
//   3) attn = (P @ V) / rowsum  (bf16 MFMA, fp16 out)
//   4) out  = attn @ W_out + b  (fp16 MFMA, fp32 out)
//
// GEMM core (new): 256x256 tile, 512 thr = 8 waves (2Mx4N, wave-tile 128x64),
// 4-slot LDS pipeline (slot = A[256][32]+B[256][32] = 32KB, 128KB total).
// Phase = one kk(32)-step: vmcnt(8) counted wait -> raw s_barrier -> stage
// slot p+3 (4 x global_load_lds, per-phase interleave) -> 12 ds_read_b128
// -> lgkmcnt(0) -> setprio(1) -> 32 MFMA. 3-phase prefetch lead, no vmcnt(0)
// drain in loop. Granule swizzle g' = fg ^ ((row>>1)&3) on both stage source
// and read (involution) -> 2-way LDS conflicts only (free).
// ---------------------------------------------------------------------------

typedef short    s16x8 __attribute__((ext_vector_type(8)));
typedef short    s16x4 __attribute__((ext_vector_type(4)));
typedef float    fx4   __attribute__((ext_vector_type(4)));
typedef _Float16 h16x8 __attribute__((ext_vector_type(8)));

__device__ __forceinline__ short f2bs(float f) {            // f32 -> bf16 bits (RNE)
  __hip_bfloat16 h = __float2bfloat16(f);
  short s; __builtin_memcpy(&s, &h, 2); return s;
}
__device__ __forceinline__ short f2hs(float f) {            // f32 -> fp16 bits (RNE)
  _Float16 h = (_Float16)f;
  short s; __builtin_memcpy(&s, &h, 2); return s;
}
__device__ __forceinline__ float b2f(short s) {             // bf16 bits -> f32
  unsigned u = ((unsigned)(unsigned short)s) << 16;
  float f; __builtin_memcpy(&f, &u, 4); return f;
}

__device__ __forceinline__ void gload16(const void* g, void* l) {
  __builtin_amdgcn_global_load_lds(
      (const __attribute__((address_space(1))) void*)g,
      (__attribute__((address_space(3))) void*)l, 16, 0, 0);
}

// ---------------- prep kernels ----------------

__global__ void cvt_f32_f16(const float* __restrict__ in, short* __restrict__ out, int n4) {
  int i = blockIdx.x * blockDim.x + threadIdx.x;
  if (i < n4) {
    float4 v = reinterpret_cast<const float4*>(in)[i];
    s16x4 o;
    o.x = f2hs(v.x); o.y = f2hs(v.y); o.z = f2hs(v.z); o.w = f2hs(v.w);
    reinterpret_cast<s16x4*>(out)[i] = o;
  }
}

__global__ void transpose_w(const float* __restrict__ W, int K, int N,
                            short* __restrict__ WT, float qscale, int scaleN) {
  __shared__ float tile[32][33];
  int k0 = blockIdx.y * 32, n0 = blockIdx.x * 32;
  int r = threadIdx.x >> 5, c = threadIdx.x & 31;
  for (int rr = r; rr < 32; rr += 8)
    tile[rr][c] = W[(size_t)(k0 + rr) * N + n0 + c];
  __syncthreads();
  for (int rr = r; rr < 32; rr += 8) {
    int n = n0 + rr;
    float s = (n < scaleN) ? qscale : 1.0f;
    WT[(size_t)n * K + k0 + c] = f2hs(tile[c][rr] * s);
  }
}

// ---------------- 256x256 4-slot pipelined GEMM ----------------
// C[M][N] = A[M][K] @ B'[N][K]^T  (16-bit operands, k-contiguous rows)
// EPI: 0 = qkv write (fp16 q/k cols <2048 -> Cv; v cols >=2048 -> bf16 VT=Cv2)
//      1 = exp -> bf16 + fused rowsum (shfl-reduce + atomicAdd into auxw)
//      2 = /aux[row] -> fp16     3 = +aux[col] -> fp32
template<int EPI, int DT>
__global__ __launch_bounds__(512, 2)
void gemm256(const short* __restrict__ A, int lda, long long bsA,
             const short* __restrict__ B, int ldb, long long bsB,
             void* __restrict__ Cv, int ldc, long long bsC,
             int K, const float* __restrict__ aux, long long bsAux,
             short* __restrict__ Cv2, float* __restrict__ auxw) {
  // 4 slots, each: A-subtile [256 rows][32 k] (16KB) + B-subtile (16KB)
  __shared__ __align__(16) short S[4][16384];

  const int t = threadIdx.x;
  const int z = blockIdx.z;
  A += (size_t)z * bsA;
  B += (size_t)z * bsB;

  const int brow = blockIdx.y * 256;
  const int bcol = blockIdx.x * 256;

  const int lane = t & 63;
  const int wid  = t >> 6;
  const int wm = wid >> 2;               // 0/1: rows wm*128..+127
  const int wn = wid & 3;                // 0..3: cols wn*64..+63
  const int fr = lane & 15;
  const int fg = lane >> 4;

  // ---- staging geometry: wave wid stages rows wid*32..wid*32+31 of A and B.
  // LDS linear granules G = wid*128 + i*64 + lane; row = G>>2, g' = G&3.
  // Source col-granule = g' ^ ((row>>1)&3)  (= (lane&3) ^ ((lane>>3)&3)).
  const int l2 = lane >> 2;
  const int gsrc = ((lane & 3) ^ ((lane >> 3) & 3)) * 8;     // shorts
  const short* Ag0 = A + (size_t)(brow + wid * 32 + l2) * lda + gsrc;
  const short* Ag1 = Ag0 + (size_t)16 * lda;
  const short* Bg0 = B + (size_t)(bcol + wid * 32 + l2) * ldb + gsrc;
  const short* Bg1 = Bg0 + (size_t)16 * ldb;
  const int dA = wid * 1024;             // LDS dest (shorts), +512 for i=1
  const int dB = 8192 + wid * 1024;

  // ---- frag-read bases: granule g' = fg ^ ((row>>1)&3); row>>1 dep = fr>>1.
  const int gq = (fg ^ ((fr >> 1) & 3)) * 8;
  const int aB = (wm * 128 + fr) * 32 + gq;                  // + m*512
  const int bB = 8192 + (wn * 64 + fr) * 32 + gq;            // + n*512

  fx4 acc[8][4] = {};
  const int Km32 = K - 32;

  auto MM = [&](s16x8 av, s16x8 bv, fx4 c) -> fx4 {
    if constexpr (DT == 0)
      return __builtin_amdgcn_mfma_f32_16x16x32_f16(
          __builtin_bit_cast(h16x8, av), __builtin_bit_cast(h16x8, bv), c, 0, 0, 0);
    else
      return __builtin_amdgcn_mfma_f32_16x16x32_bf16(av, bv, c, 0, 0, 0);
  };

  // prologue: slots 0,1,2 <- k-windows 0,32,64 (12 loads outstanding)
#pragma unroll
  for (int s = 0; s < 3; ++s) {
    const int kk = s * 32;
    gload16(Ag0 + kk, &S[s][dA]);
    gload16(Ag1 + kk, &S[s][dA + 512]);
    gload16(Bg0 + kk, &S[s][dB]);
    gload16(Bg1 + kk, &S[s][dB + 512]);
  }
  int knext = 96;

  const int NPH = K >> 5;                // phases; all K are multiples of 128
  for (int p = 0; p < NPH; p += 4) {
#define PHASE(SLOT)                                                          \
    {                                                                        \
      asm volatile("s_waitcnt vmcnt(8)" ::: "memory");  /* slot landed */    \
      __builtin_amdgcn_s_barrier();                     /* raw, no drain */  \
      const int kk = knext <= Km32 ? knext : Km32;      /* clamped stage */  \
      short* D = &S[(SLOT + 3) & 3][0];                                      \
      gload16(Ag0 + kk, D + dA);                                             \
      gload16(Ag1 + kk, D + dA + 512);                                       \
      gload16(Bg0 + kk, D + dB);                                             \
      gload16(Bg1 + kk, D + dB + 512);                                       \
      knext += 32;                                                           \
      const short* Sl = &S[SLOT][0];                                         \
      s16x8 a[8], b[4];                                                      \
      _Pragma("unroll")                                                      \
      for (int m = 0; m < 8; ++m)                                            \
        a[m] = *reinterpret_cast<const s16x8*>(&Sl[aB + m * 512]);           \
      _Pragma("unroll")                                                      \
      for (int n = 0; n < 4; ++n)                                            \
        b[n] = *reinterpret_cast<const s16x8*>(&Sl[bB + n * 512]);           \
      asm volatile("s_waitcnt lgkmcnt(0)" ::: "memory");                     \
      __builtin_amdgcn_sched_barrier(0);                                     \
      __builtin_amdgcn_s_setprio(1);                                         \
      _Pragma("unroll")                                                      \
      for (int m = 0; m < 8; ++m)                                            \
        _Pragma("unroll")                                                    \
        for (int n = 0; n < 4; ++n)                                          \
          acc[m][n] = MM(a[m], b[n], acc[m][n]);                             \
      __builtin_amdgcn_s_setprio(0);                                         \
    }
    PHASE(0) PHASE(1) PHASE(2) PHASE(3)
#undef PHASE
  }
  // drain tail DMA before block exit (LDS may be re-allocated to next block)
  asm volatile("s_waitcnt vmcnt(0)" ::: "memory");

  // ---- epilogue: D row = fg*4 + j, col = fr (per 16x16 frag) ----
  const int row0 = brow + wm * 128 + fg * 4;
  const int col0 = bcol + wn * 64 + fr;
  const float* auxp = aux + (size_t)z * bsAux;

  if constexpr (EPI == 3) {
    float* Cf = reinterpret_cast<float*>(Cv) + (size_t)z * bsC;
#pragma unroll
    for (int m = 0; m < 8; ++m)
#pragma unroll
      for (int n = 0; n < 4; ++n) {
        const int col = col0 + n * 16;
        const float bo = auxp[col];
#pragma unroll
        for (int j = 0; j < 4; ++j)
          Cf[(size_t)(row0 + m * 16 + j) * ldc + col] = acc[m][n][j] + bo;
      }
  } else if constexpr (EPI == 0) {
    short* Cb = reinterpret_cast<short*>(Cv);
    if (bcol < 2048) {                    // q/k columns -> fp16, row-major
#pragma unroll
      for (int m = 0; m < 8; ++m)
#pragma unroll
        for (int j = 0; j < 4; ++j) {
          const int row = row0 + m * 16 + j;
#pragma unroll
          for (int n = 0; n < 4; ++n)
            Cb[(size_t)row * ldc + col0 + n * 16] = f2hs(acc[m][n][j]);
        }
    } else {                              // v columns -> bf16 into VT[b][d][t]
#pragma unroll
      for (int m = 0; m < 8; ++m)
#pragma unroll
        for (int j = 0; j < 4; ++j) {
          const int row = row0 + m * 16 + j;
          const int zb = row >> 11, s = row & 2047;
#pragma unroll
          for (int n = 0; n < 4; ++n) {
            const int d = col0 + n * 16 - 2048;
            Cv2[((size_t)(zb << 10) + d) * 2048 + s] = f2bs(acc[m][n][j]);
          }
        }
    }
  } else if constexpr (EPI == 1) {
    // P = exp(dots) bf16; fused row-sum: 4 vals/lane over 16-lane fr-group
    // (64 cols/wave), shfl-xor reduce, 1 atomicAdd per (row, wave).
    short* Cb = reinterpret_cast<short*>(Cv) + (size_t)z * bsC;
    float* rs_out = auxw + (size_t)z * bsAux;
#pragma unroll
    for (int m = 0; m < 8; ++m)
#pragma unroll
      for (int j = 0; j < 4; ++j) {
        const int row = row0 + m * 16 + j;
        float e[4];
#pragma unroll
        for (int n = 0; n < 4; ++n) {
          e[n] = exp2f(acc[m][n][j] * 1.4426950408889634f);
          Cb[(size_t)row * ldc + col0 + n * 16] = f2bs(e[n]);
        }
        float ps = (e[0] + e[1]) + (e[2] + e[3]);
        ps += __shfl_xor(ps, 1);
        ps += __shfl_xor(ps, 2);
        ps += __shfl_xor(ps, 4);
        ps += __shfl_xor(ps, 8);
        if (fr == 0) atomicAdd(&rs_out[row], ps);
      }
  } else {                                // EPI == 2: attn = acc / rowsum
    short* Cb = reinterpret_cast<short*>(Cv) + (size_t)z * bsC;
#pragma unroll
    for (int m = 0; m < 8; ++m)
#pragma unroll
      for (int j = 0; j < 4; ++j) {
        const int row = row0 + m * 16 + j;
        const float rs = 1.0f / auxp[row];
#pragma unroll
        for (int n = 0; n < 4; ++n)
          Cb[(size_t)row * ldc + col0 + n * 16] = f2hs(acc[m][n][j] * rs);
      }
  }
}

// ---------------- launch ----------------

extern "C" void kernel_launch(void* const* d_in, const int* in_sizes, int n_in,
                              void* d_out, int out_size, void* d_ws, size_t ws_size,
                              hipStream_t stream) {
  const float* x    = (const float*)d_in[0];   // [4,2048,1024]
  const float* Wqkv = (const float*)d_in[1];   // [1024,3072]
  const float* Wout = (const float*)d_in[2];   // [1024,1024]
  const float* bout = (const float*)d_in[3];   // [1024]
  float* out = (float*)d_out;                  // [4,2048,1024] fp32

  // workspace layout (bytes)
  char* ws = (char*)d_ws;
  short* qkv   = (short*)(ws + 0);             //  50331648  q/k fp16 [8192][3072]
  short* WqkvT = (short*)(ws + 50331648);      //   6291456  fp16 [3072][1024]
  short* WoutT = (short*)(ws + 56623104);      //   2097152  fp16 [1024][1024]
  short* P     = (short*)(ws + 58720256);      //  33554432  bf16 [4][2048][2048]
  short* VT    = (short*)(ws + 92274688);      //  16777216  bf16 [4][1024][2048]
  short* xh    = (short*)(ws + 109051904);     //  16777216  fp16 x (reused as attn)
  float* rsum  = (float*)(ws + 125829120);     //     32768  [4][2048] row sums
  if (ws_size < 125861888) return;             // insufficient scratch -> visible failure
  short* attn = xh;                            // x_fp16 dead after qkv GEMM

  hipMemsetAsync(rsum, 0, 8192 * sizeof(float), stream);
  cvt_f32_f16<<<8192, 256, 0, stream>>>(x, xh, 8388608 / 4);
  transpose_w<<<dim3(96, 32), 256, 0, stream>>>(Wqkv, 1024, 3072, WqkvT, 0.125f, 1024);
  transpose_w<<<dim3(32, 32), 256, 0, stream>>>(Wout, 1024, 1024, WoutT, 1.0f, 0);

  // qkv = x @ W_qkv   (q/k -> qkv buf; v -> VT transposed)
  gemm256<0, 0><<<dim3(12, 32, 1), 512, 0, stream>>>(
      xh, 1024, 0, WqkvT, 1024, 0, qkv, 3072, 0, 1024, bout, 0, VT, nullptr);
  // P = exp(q @ k^T) + fused rowsum   (scale folded into Wq)
  gemm256<1, 0><<<dim3(8, 8, 4), 512, 0, stream>>>(
      qkv, 3072, 2048LL * 3072, qkv + 1024, 3072, 2048LL * 3072,
      P, 2048, 2048LL * 2048, 1024, bout, 2048, nullptr, rsum);
  // attn = (P @ V) / rowsum
  gemm256<2, 1><<<dim3(4, 8, 4), 512, 0, stream>>>(
      P, 2048, 2048LL * 2048, VT, 2048, 1024LL * 2048,
      attn, 1024, 2048LL * 1024, 2048, rsum, 2048, nullptr, nullptr);
  // out = attn @ W_out + b
  gemm256<3, 0><<<dim3(4, 32, 1), 512, 0, stream>>>(
      attn, 1024, 0, WoutT, 1024, 0, out, 1024, 0, 1024, bout, 0, nullptr, nullptr);
}

// Round 8
// 217.642 us; speedup vs baseline: 1.0019x; 1.0019x over previous
//
#include <hip/hip_runtime.h>
#include <hip/hip_bf16.h>

// ---------------------------------------------------------------------------
// Attention_58248346469030:  out = softmax((x@Wq)(x@Wk)^T * sc) @ (x@Wv) @ Wout + b
// B=4, S=2048, DIM=1024, INNER=1024 (full-dim attention, no head split).
//
// Pipeline (fp16/bf16 MFMA, fp32 accumulate):
//   prep:  x -> fp16;  W_qkv -> fp16 transposed [n][k] (q pre-scaled by 0.125);
//          W_out -> fp16 transposed.
//   1) qkv  = x @ W_qkv       (q/k fp16 row-major; v bf16 written transposed->VT)
//   2) P    = exp(q @ k^T)    (fp16 MFMA, bf16 out; rowsum fused shfl+atomicAdd)
//   3) attn = (P @ V) / rowsum  (bf16 MFMA, fp16 out)
//   4) out  = attn @ W_out + b  (fp16 MFMA, fp32 out)
//
// GEMM core: 256x256 tile, 8 waves (2Mx4N, wave-tile 128x64), 4-slot LDS
// (32KB/slot, 128KB). REGISTER PING-PONG (new this round): phase p issues
// ds_reads of slot p+1 into the next reg set, then MFMAs the current set —
// LDS issue+bank+latency hides under the 1243-cyc MFMA window instead of
// sitting serially in front of it. vmcnt(4) counted cert (2-phase-old loads),
// one barrier/phase, setprio around MFMA, granule-XOR swizzle (2-way = free).
// ---------------------------------------------------------------------------

typedef short    s16x8 __attribute__((ext_vector_type(8)));
typedef short    s16x4 __attribute__((ext_vector_type(4)));
typedef float    fx4   __attribute__((ext_vector_type(4)));
typedef _Float16 h16x8 __attribute__((ext_vector_type(8)));

__device__ __forceinline__ short f2bs(float f) {            // f32 -> bf16 bits (RNE)
  __hip_bfloat16 h = __float2bfloat16(f);
  short s; __builtin_memcpy(&s, &h, 2); return s;
}
__device__ __forceinline__ short f2hs(float f) {            // f32 -> fp16 bits (RNE)
  _Float16 h = (_Float16)f;
  short s; __builtin_memcpy(&s, &h, 2); return s;
}

__device__ __forceinline__ void gload16(const void* g, void* l) {
  __builtin_amdgcn_global_load_lds(
      (const __attribute__((address_space(1))) void*)g,
      (__attribute__((address_space(3))) void*)l, 16, 0, 0);
}

// ---------------- prep kernels ----------------

__global__ void cvt_f32_f16(const float* __restrict__ in, short* __restrict__ out, int n4) {
  int i = blockIdx.x * blockDim.x + threadIdx.x;
  if (i < n4) {
    float4 v = reinterpret_cast<const float4*>(in)[i];
    s16x4 o;
    o.x = f2hs(v.x); o.y = f2hs(v.y); o.z = f2hs(v.z); o.w = f2hs(v.w);
    reinterpret_cast<s16x4*>(out)[i] = o;
  }
}

__global__ void transpose_w(const float* __restrict__ W, int K, int N,
                            short* __restrict__ WT, float qscale, int scaleN) {
  __shared__ float tile[32][33];
  int k0 = blockIdx.y * 32, n0 = blockIdx.x * 32;
  int r = threadIdx.x >> 5, c = threadIdx.x & 31;
  for (int rr = r; rr < 32; rr += 8)
    tile[rr][c] = W[(size_t)(k0 + rr) * N + n0 + c];
  __syncthreads();
  for (int rr = r; rr < 32; rr += 8) {
    int n = n0 + rr;
    float s = (n < scaleN) ? qscale : 1.0f;
    WT[(size_t)n * K + k0 + c] = f2hs(tile[c][rr] * s);
  }
}

// ---------------- 256x256 4-slot ping-pong GEMM ----------------
// C[M][N] = A[M][K] @ B'[N][K]^T  (16-bit operands, k-contiguous rows)
// EPI: 0 = qkv write (fp16 q/k cols <2048 -> Cv; v cols >=2048 -> bf16 VT=Cv2)
//      1 = exp -> bf16 + fused rowsum (shfl-reduce + atomicAdd into auxw)
//      2 = /aux[row] -> fp16     3 = +aux[col] -> fp32
template<int EPI, int DT>
__global__ __launch_bounds__(512, 2)
void gemm256(const short* __restrict__ A, int lda, long long bsA,
             const short* __restrict__ B, int ldb, long long bsB,
             void* __restrict__ Cv, int ldc, long long bsC,
             int K, const float* __restrict__ aux, long long bsAux,
             short* __restrict__ Cv2, float* __restrict__ auxw) {
  // 4 slots, each: A-subtile [256 rows][32 k] (16KB) + B-subtile (16KB)
  __shared__ __align__(16) short S[4][16384];

  const int t = threadIdx.x;
  const int z = blockIdx.z;
  A += (size_t)z * bsA;
  B += (size_t)z * bsB;

  const int brow = blockIdx.y * 256;
  const int bcol = blockIdx.x * 256;

  const int lane = t & 63;
  const int wid  = t >> 6;
  const int wm = wid >> 2;               // 0/1: rows wm*128..+127
  const int wn = wid & 3;                // 0..3: cols wn*64..+63
  const int fr = lane & 15;
  const int fg = lane >> 4;

  // ---- staging geometry: wave wid stages rows wid*32..wid*32+31 of A and B.
  // LDS linear granules G = wid*128 + i*64 + lane; row = G>>2, g' = G&3.
  // Source col-granule = g' ^ ((row>>1)&3)  (= (lane&3) ^ ((lane>>3)&3)).
  const int l2 = lane >> 2;
  const int gsrc = ((lane & 3) ^ ((lane >> 3) & 3)) * 8;     // shorts
  const short* Ag0 = A + (size_t)(brow + wid * 32 + l2) * lda + gsrc;
  const short* Ag1 = Ag0 + (size_t)16 * lda;
  const short* Bg0 = B + (size_t)(bcol + wid * 32 + l2) * ldb + gsrc;
  const short* Bg1 = Bg0 + (size_t)16 * ldb;
  const int dA = wid * 1024;             // LDS dest (shorts), +512 for i=1
  const int dB = 8192 + wid * 1024;

  // ---- frag-read bases: granule g' = fg ^ ((row>>1)&3); row>>1 dep = fr>>1.
  const int gq = (fg ^ ((fr >> 1) & 3)) * 8;
  const int aB = (wm * 128 + fr) * 32 + gq;                  // + m*512
  const int bB = 8192 + (wn * 64 + fr) * 32 + gq;            // + n*512

  fx4 acc[8][4] = {};
  s16x8 ra[2][8], rb[2][4];              // ping-pong fragment sets
  const int Km32 = K - 32;

  auto MM = [&](s16x8 av, s16x8 bv, fx4 c) -> fx4 {
    if constexpr (DT == 0)
      return __builtin_amdgcn_mfma_f32_16x16x32_f16(
          __builtin_bit_cast(h16x8, av), __builtin_bit_cast(h16x8, bv), c, 0, 0, 0);
    else
      return __builtin_amdgcn_mfma_f32_16x16x32_bf16(av, bv, c, 0, 0, 0);
  };

  // prologue: slots 0,1,2 <- k-windows 0,32,64 (12 loads outstanding)
#pragma unroll
  for (int s = 0; s < 3; ++s) {
    const int kk = s * 32;
    gload16(Ag0 + kk, &S[s][dA]);
    gload16(Ag1 + kk, &S[s][dA + 512]);
    gload16(Bg0 + kk, &S[s][dB]);
    gload16(Bg1 + kk, &S[s][dB + 512]);
  }
  asm volatile("s_waitcnt vmcnt(8)" ::: "memory");   // slot 0 landed (own)
  __builtin_amdgcn_s_barrier();                      // publish slot 0
#pragma unroll
  for (int m = 0; m < 8; ++m)
    ra[0][m] = *reinterpret_cast<const s16x8*>(&S[0][aB + m * 512]);
#pragma unroll
  for (int n = 0; n < 4; ++n)
    rb[0][n] = *reinterpret_cast<const s16x8*>(&S[0][bB + n * 512]);
  int knext = 96;

  // Phase p: certify slot p+1 (vmcnt(4): its loads are 2 phases old) ->
  // barrier -> stage slot p+3 -> issue ds_reads of slot p+1 into set NXT ->
  // MFMA set CUR (reads issued last phase; compiler emits counted lgkm wait).
#define PHASE(SLOT, CUR, NXT)                                                \
  {                                                                          \
    asm volatile("s_waitcnt vmcnt(4)" ::: "memory");                         \
    __builtin_amdgcn_s_barrier();                                            \
    const int kk = knext <= Km32 ? knext : Km32;                             \
    short* D = &S[(SLOT + 3) & 3][0];                                        \
    gload16(Ag0 + kk, D + dA);                                               \
    gload16(Ag1 + kk, D + dA + 512);                                         \
    gload16(Bg0 + kk, D + dB);                                               \
    gload16(Bg1 + kk, D + dB + 512);                                         \
    knext += 32;                                                             \
    const short* Sl = &S[(SLOT + 1) & 3][0];                                 \
    _Pragma("unroll")                                                        \
    for (int m = 0; m < 8; ++m)                                              \
      ra[NXT][m] = *reinterpret_cast<const s16x8*>(&Sl[aB + m * 512]);       \
    _Pragma("unroll")                                                        \
    for (int n = 0; n < 4; ++n)                                              \
      rb[NXT][n] = *reinterpret_cast<const s16x8*>(&Sl[bB + n * 512]);       \
    __builtin_amdgcn_sched_barrier(0);                                       \
    __builtin_amdgcn_s_setprio(1);                                           \
    _Pragma("unroll")                                                        \
    for (int m = 0; m < 8; ++m)                                              \
      _Pragma("unroll")                                                      \
      for (int n = 0; n < 4; ++n)                                            \
        acc[m][n] = MM(ra[CUR][m], rb[CUR][n], acc[m][n]);                   \
    __builtin_amdgcn_s_setprio(0);                                           \
  }

  const int NPH = K >> 5;                // all K multiples of 128 -> NPH % 4 == 0
  for (int p = 0; p < NPH; p += 4) {
    PHASE(0, 0, 1) PHASE(1, 1, 0) PHASE(2, 0, 1) PHASE(3, 1, 0)
  }
#undef PHASE
  // drain tail DMA before block exit (LDS may be re-allocated to next block)
  asm volatile("s_waitcnt vmcnt(0)" ::: "memory");

  // ---- epilogue: D row = fg*4 + j, col = fr (per 16x16 frag) ----
  const int row0 = brow + wm * 128 + fg * 4;
  const int col0 = bcol + wn * 64 + fr;
  const float* auxp = aux + (size_t)z * bsAux;

  if constexpr (EPI == 3) {
    float* Cf = reinterpret_cast<float*>(Cv) + (size_t)z * bsC;
#pragma unroll
    for (int m = 0; m < 8; ++m)
#pragma unroll
      for (int n = 0; n < 4; ++n) {
        const int col = col0 + n * 16;
        const float bo = auxp[col];
#pragma unroll
        for (int j = 0; j < 4; ++j)
          Cf[(size_t)(row0 + m * 16 + j) * ldc + col] = acc[m][n][j] + bo;
      }
  } else if constexpr (EPI == 0) {
    short* Cb = reinterpret_cast<short*>(Cv);
    if (bcol < 2048) {                    // q/k columns -> fp16, row-major
#pragma unroll
      for (int m = 0; m < 8; ++m)
#pragma unroll
        for (int j = 0; j < 4; ++j) {
          const int row = row0 + m * 16 + j;
#pragma unroll
          for (int n = 0; n < 4; ++n)
            Cb[(size_t)row * ldc + col0 + n * 16] = f2hs(acc[m][n][j]);
        }
    } else {                              // v columns -> bf16 into VT[b][d][t]
#pragma unroll
      for (int m = 0; m < 8; ++m)
#pragma unroll
        for (int j = 0; j < 4; ++j) {
          const int row = row0 + m * 16 + j;
          const int zb = row >> 11, s = row & 2047;
#pragma unroll
          for (int n = 0; n < 4; ++n) {
            const int d = col0 + n * 16 - 2048;
            Cv2[((size_t)(zb << 10) + d) * 2048 + s] = f2bs(acc[m][n][j]);
          }
        }
    }
  } else if constexpr (EPI == 1) {
    // P = exp(dots) bf16; fused row-sum: 4 vals/lane over 16-lane fr-group
    // (64 cols/wave), shfl-xor reduce, 1 atomicAdd per (row, wave).
    short* Cb = reinterpret_cast<short*>(Cv) + (size_t)z * bsC;
    float* rs_out = auxw + (size_t)z * bsAux;
#pragma unroll
    for (int m = 0; m < 8; ++m)
#pragma unroll
      for (int j = 0; j < 4; ++j) {
        const int row = row0 + m * 16 + j;
        float e[4];
#pragma unroll
        for (int n = 0; n < 4; ++n) {
          e[n] = exp2f(acc[m][n][j] * 1.4426950408889634f);
          Cb[(size_t)row * ldc + col0 + n * 16] = f2bs(e[n]);
        }
        float ps = (e[0] + e[1]) + (e[2] + e[3]);
        ps += __shfl_xor(ps, 1);
        ps += __shfl_xor(ps, 2);
        ps += __shfl_xor(ps, 4);
        ps += __shfl_xor(ps, 8);
        if (fr == 0) atomicAdd(&rs_out[row], ps);
      }
  } else {                                // EPI == 2: attn = acc / rowsum
    short* Cb = reinterpret_cast<short*>(Cv) + (size_t)z * bsC;
#pragma unroll
    for (int m = 0; m < 8; ++m)
#pragma unroll
      for (int j = 0; j < 4; ++j) {
        const int row = row0 + m * 16 + j;
        const float rs = 1.0f / auxp[row];
#pragma unroll
        for (int n = 0; n < 4; ++n)
          Cb[(size_t)row * ldc + col0 + n * 16] = f2hs(acc[m][n][j] * rs);
      }
  }
}

// ---------------- launch ----------------

extern "C" void kernel_launch(void* const* d_in, const int* in_sizes, int n_in,
                              void* d_out, int out_size, void* d_ws, size_t ws_size,
                              hipStream_t stream) {
  const float* x    = (const float*)d_in[0];   // [4,2048,1024]
  const float* Wqkv = (const float*)d_in[1];   // [1024,3072]
  const float* Wout = (const float*)d_in[2];   // [1024,1024]
  const float* bout = (const float*)d_in[3];   // [1024]
  float* out = (float*)d_out;                  // [4,2048,1024] fp32

  // workspace layout (bytes)
  char* ws = (char*)d_ws;
  short* qkv   = (short*)(ws + 0);             //  50331648  q/k fp16 [8192][3072]
  short* WqkvT = (short*)(ws + 50331648);      //   6291456  fp16 [3072][1024]
  short* WoutT = (short*)(ws + 56623104);      //   2097152  fp16 [1024][1024]
  short* P     = (short*)(ws + 58720256);      //  33554432  bf16 [4][2048][2048]
  short* VT    = (short*)(ws + 92274688);      //  16777216  bf16 [4][1024][2048]
  short* xh    = (short*)(ws + 109051904);     //  16777216  fp16 x (reused as attn)
  float* rsum  = (float*)(ws + 125829120);     //     32768  [4][2048] row sums
  if (ws_size < 125861888) return;             // insufficient scratch -> visible failure
  short* attn = xh;                            // x_fp16 dead after qkv GEMM

  hipMemsetAsync(rsum, 0, 8192 * sizeof(float), stream);
  cvt_f32_f16<<<8192, 256, 0, stream>>>(x, xh, 8388608 / 4);
  transpose_w<<<dim3(96, 32), 256, 0, stream>>>(Wqkv, 1024, 3072, WqkvT, 0.125f, 1024);
  transpose_w<<<dim3(32, 32), 256, 0, stream>>>(Wout, 1024, 1024, WoutT, 1.0f, 0);

  // qkv = x @ W_qkv   (q/k -> qkv buf; v -> VT transposed)
  gemm256<0, 0><<<dim3(12, 32, 1), 512, 0, stream>>>(
      xh, 1024, 0, WqkvT, 1024, 0, qkv, 3072, 0, 1024, bout, 0, VT, nullptr);
  // P = exp(q @ k^T) + fused rowsum   (scale folded into Wq)
  gemm256<1, 0><<<dim3(8, 8, 4), 512, 0, stream>>>(
      qkv, 3072, 2048LL * 3072, qkv + 1024, 3072, 2048LL * 3072,
      P, 2048, 2048LL * 2048, 1024, bout, 2048, nullptr, rsum);
  // attn = (P @ V) / rowsum
  gemm256<2, 1><<<dim3(4, 8, 4), 512, 0, stream>>>(
      P, 2048, 2048LL * 2048, VT, 2048, 1024LL * 2048,
      attn, 1024, 2048LL * 1024, 2048, rsum, 2048, nullptr, nullptr);
  // out = attn @ W_out + b
  gemm256<3, 0><<<dim3(4, 32, 1), 512, 0, stream>>>(
      attn, 1024, 0, WoutT, 1024, 0, out, 1024, 0, 1024, bout, 0, nullptr, nullptr);
}